// Round 6
// baseline (262.543 us; speedup 1.0000x reference)
//
#include <hip/hip_runtime.h>
#include <cstdint>
#include <cstddef>

// FusedBitLinear: RMSNorm -> ternary W quant (absmean) -> int8 activation quant
// -> int GEMM (MFMA i8) -> rescale by alpha*gamma[m]/127.
//
// M=4096 tokens, K=4096, N=4096. fp32 in/out.
//
// ws layout:
//   [0, 16M)            xq   int8 [4096][4096]
//   [16M, 32M)          wq   int8 [4096][4096]
//   [32M, +16KB)        gamma float[4096]
//   [+16KB, +32KB)      alpha partials float[4096]
//   [+32KB, +4B)        alpha float[1]

#define KD 4096
#define MD 4096
#define ND 4096

#define WBLK 512

typedef int i32x4 __attribute__((ext_vector_type(4)));

// async global->LDS, 16B per lane; lds dst is wave-uniform base (+lane*16)
__device__ __forceinline__ void gl2lds16(const signed char* g, signed char* l) {
  __builtin_amdgcn_global_load_lds(
      (const __attribute__((address_space(1))) void*)g,
      (__attribute__((address_space(3))) void*)l, 16, 0, 0);
}

__device__ __forceinline__ float wave_sum(float v) {
#pragma unroll
  for (int off = 32; off; off >>= 1) v += __shfl_down(v, off, 64);
  return v;
}
__device__ __forceinline__ float wave_max(float v) {
#pragma unroll
  for (int off = 32; off; off >>= 1) v = fmaxf(v, __shfl_down(v, off, 64));
  return v;
}

// ---------------- pass 1: per-row |W| partial sums (UNCHANGED) ------------

__global__ __launch_bounds__(256) void k_alpha_part(const float* __restrict__ w,
                                                    float* __restrict__ part) {
  __shared__ float red[4];
  const int tid = threadIdx.x;
  const float4* w4 = (const float4*)(w + (size_t)blockIdx.x * 4096);
  float s = 0.f;
#pragma unroll
  for (int i = 0; i < 4; ++i) {
    float4 v = w4[i * 256 + tid];
    s += fabsf(v.x) + fabsf(v.y) + fabsf(v.z) + fabsf(v.w);
  }
  s = wave_sum(s);
  if ((tid & 63) == 0) red[tid >> 6] = s;
  __syncthreads();
  if (tid == 0) part[blockIdx.x] = (red[0] + red[1]) + (red[2] + red[3]);
}

// ---------------- pass 2: fused quantization (UNCHANGED) ------------------

__device__ __forceinline__ uint32_t qw4(float4 v, float alpha) {
  int q0 = (int)fminf(fmaxf(rintf(v.x / alpha), -1.f), 1.f);
  int q1 = (int)fminf(fmaxf(rintf(v.y / alpha), -1.f), 1.f);
  int q2 = (int)fminf(fmaxf(rintf(v.z / alpha), -1.f), 1.f);
  int q3 = (int)fminf(fmaxf(rintf(v.w / alpha), -1.f), 1.f);
  return (uint32_t)(q0 & 255) | ((uint32_t)(q1 & 255) << 8) |
         ((uint32_t)(q2 & 255) << 16) | ((uint32_t)(q3 & 255) << 24);
}

__global__ __launch_bounds__(256) void k_quant_all(const float* __restrict__ w,
                                                   const float* __restrict__ x,
                                                   const float* __restrict__ nw,
                                                   const float* __restrict__ part,
                                                   signed char* __restrict__ wq,
                                                   signed char* __restrict__ xq,
                                                   float* __restrict__ gamma,
                                                   float* __restrict__ alpha_out) {
  const int tid = threadIdx.x;
  const int bid = blockIdx.x;
  __shared__ float red[4];
  __shared__ float red2[4];

  if (bid < 4096) {
    const int row = bid;
    const float4* x4 = (const float4*)(x + (size_t)row * 4096);
    const float4* n4 = (const float4*)nw;
    float4 xv[4], nv[4];
#pragma unroll
    for (int i = 0; i < 4; ++i) {
      xv[i] = x4[i * 256 + tid];
      nv[i] = n4[i * 256 + tid];
    }
    float ss = 0.f, mx = 0.f;
#pragma unroll
    for (int i = 0; i < 4; ++i) {
      ss += xv[i].x * xv[i].x + xv[i].y * xv[i].y + xv[i].z * xv[i].z +
            xv[i].w * xv[i].w;
      mx = fmaxf(mx,
                 fmaxf(fmaxf(fabsf(xv[i].x * nv[i].x), fabsf(xv[i].y * nv[i].y)),
                       fmaxf(fabsf(xv[i].z * nv[i].z), fabsf(xv[i].w * nv[i].w))));
    }
    ss = wave_sum(ss);
    mx = wave_max(mx);
    if ((tid & 63) == 0) {
      red[tid >> 6] = ss;
      red2[tid >> 6] = mx;
    }
    __syncthreads();
    const float tot = (red[0] + red[1]) + (red[2] + red[3]);
    const float rms = sqrtf(tot * (1.0f / 4096.0f) + 1e-6f);
    const float mxr = fmaxf(fmaxf(red2[0], red2[1]), fmaxf(red2[2], red2[3]));
    const float g = fmaxf(mxr / rms, 1e-10f);
    if (tid == 0) gamma[row] = g;
    const float inv = 127.0f / (rms * g);

    uint32_t* xqi = (uint32_t*)(xq + (size_t)row * 4096);
#pragma unroll
    for (int i = 0; i < 4; ++i) {
      const int f = i * 256 + tid;
      int q0 = (int)fminf(fmaxf(rintf(xv[i].x * nv[i].x * inv), -128.f), 127.f);
      int q1 = (int)fminf(fmaxf(rintf(xv[i].y * nv[i].y * inv), -128.f), 127.f);
      int q2 = (int)fminf(fmaxf(rintf(xv[i].z * nv[i].z * inv), -128.f), 127.f);
      int q3 = (int)fminf(fmaxf(rintf(xv[i].w * nv[i].w * inv), -128.f), 127.f);
      xqi[f] = (uint32_t)(q0 & 255) | ((uint32_t)(q1 & 255) << 8) |
               ((uint32_t)(q2 & 255) << 16) | ((uint32_t)(q3 & 255) << 24);
    }
  } else {
    const int wb = bid - 4096;
    float s = 0.f;
#pragma unroll
    for (int i = 0; i < 16; ++i) s += part[i * 256 + tid];
    s = wave_sum(s);
    if ((tid & 63) == 0) red[tid >> 6] = s;
    __syncthreads();
    const float alpha =
        fmaxf(((red[0] + red[1]) + (red[2] + red[3])) * (1.0f / 16777216.0f),
              1e-10f);
    if (wb == 0 && tid == 0) alpha_out[0] = alpha;

    const float4* w4 = (const float4*)w;
    uint32_t* wqi = (uint32_t*)wq;
#pragma unroll 1
    for (int k = 0; k < 32; k += 4) {
      const int f0 = (wb * 32 + k) * 256 + tid;
      float4 v0 = w4[f0];
      float4 v1 = w4[f0 + 256];
      float4 v2 = w4[f0 + 512];
      float4 v3 = w4[f0 + 768];
      wqi[f0] = qw4(v0, alpha);
      wqi[f0 + 256] = qw4(v1, alpha);
      wqi[f0 + 512] = qw4(v2, alpha);
      wqi[f0 + 768] = qw4(v3, alpha);
    }
  }
}

// ------------- int8 GEMM: y[m,n] = (xq . wq^T) * alpha*gamma[m]/127 -------
// 256x256 tile, BK=64, 8 waves (2M x 4N), per-wave 128x64 = 8x4 frags of
// 16x16 via mfma_i32_16x16x64_i8.
//
// ROUND-6 CHANGE: B BYPASSES LDS. Evidence: r0/r3/r4/r5 all pin MfmaUtil at
// 31-35%; per-tile arithmetic: MFMA floor 1306 cyc (per-SIMD, parallel) vs
// LDS-port demand ~1400 cyc (per-CU shared: 96 ds_read_b128 + 32 KB staged
// writes) -> even perfect overlap caps at ~37 us; measured 2914 cyc/tile =
// fully serialized. The traffic, not the schedule, is the lever. B-frags are
// now prefetched ONE FULL K-TILE ahead from global into registers (bfn, 4x
// global_load_dwordx4 per wave at p0; ~1300 cyc of MFMA cover vs ~200-400 cyc
// L2 latency; wq is L2/L3-resident, wave-pairs {i,i+4} share addresses). A
// wave's B-read = 16 rows x 64 B contiguous segments -> clean L2 requests.
// A stays in the verified LDS double-buffer. New per-tile LDS demand:
// 16 KB write + 64 KB read ~ 900 cyc < 1306 MFMA floor -> LDS port no longer
// binding. LDS shrinks 64->32 KB. r3's barrier cadence kept (beat free-run).
//
// B frag from global (verified layout): lane byte j of 16 must be
// wq[(bn+wn+ni*16+l16)*KD + t*64 + quad*16 + j] — a single dwordx4.
// A swizzle (verified, 0 conflicts): LDS chunk p of row R holds src chunk
// p ^ ((R>>1)&3); staging lane l -> row +(l>>2), pos (l&3), src (l&3)^((l>>3)&3);
// read pos = quad ^ ((l16>>1)&3). A frag byte j: k = quad*16+j, m = lane&15.
// C/D: col = lane&15, row = quad*4 + reg (verified r0).

#define BM 256
#define BN 256
#define BK 64

__global__ __launch_bounds__(512, 2) void k_gemm(const signed char* __restrict__ xq,
                                                 const signed char* __restrict__ wq,
                                                 const float* __restrict__ gamma,
                                                 const float* __restrict__ alpha_p,
                                                 float* __restrict__ out) {
  __shared__ __align__(16) signed char As_[2 * 16384];
  const int tid = threadIdx.x;
  const int lane = tid & 63;
  const int wave = tid >> 6;         // 0..7
  const int wm = (wave >> 2) * 128;  // 0 or 128
  const int wn = (wave & 3) * 64;    // 0..192
  const int quad = lane >> 4;
  const int l16 = lane & 15;

  // XCD-aware bijective remap (r5, FETCH 73.8->49.2 MB): XCD gets 4x8 rect.
  const int x = blockIdx.x & 7;
  const int r = blockIdx.x >> 3;  // 0..31
  const int bm = ((x & 3) * 4 + (r >> 3)) * BM;
  const int bn = ((x >> 2) * 8 + (r & 7)) * BN;

  // A staging: wave w, line j (j=0,1) covers rows [(j*8+w)*16, +16).
  const int lr = lane >> 2;
  const int sc = (lane & 3) ^ ((lane >> 3) & 3);
  const int rb0 = wave * 16;
  const int rb1 = (8 + wave) * 16;
  const signed char* ag0 = xq + (size_t)(bm + rb0 + lr) * KD + sc * 16;
  const signed char* ag1 = xq + (size_t)(bm + rb1 + lr) * KD + sc * 16;
  const int lA0 = rb0 * BK;
  const int lA1 = rb1 * BK;

  const int pos = (quad ^ ((l16 >> 1) & 3)) * 16;

  // B global fragment pointers (one per ni), advanced by k each tile.
  const signed char* bgf[4];
#pragma unroll
  for (int ni = 0; ni < 4; ++ni)
    bgf[ni] = wq + (size_t)(bn + wn + ni * 16 + l16) * KD + quad * 16;

  i32x4 acc[8][4];
#pragma unroll
  for (int i = 0; i < 8; ++i)
#pragma unroll
    for (int j = 0; j < 4; ++j) acc[i][j] = (i32x4){0, 0, 0, 0};

  i32x4 bf[4], bfn[4], af[2];

  // ---- prologue: stage A tile 0, load B frags for tile 0 ----
  gl2lds16(ag0, As_ + lA0);
  gl2lds16(ag1, As_ + lA1);
#pragma unroll
  for (int ni = 0; ni < 4; ++ni) bf[ni] = *(const i32x4*)bgf[ni];
  __syncthreads();  // drains vmcnt(0) -> A tile 0 resident (and bf loaded)

  for (int t = 0; t < 64; ++t) {
    const int c = t & 1;
    const signed char* Ab = As_ + c * 16384;
    signed char* An = As_ + (c ^ 1) * 16384;
    const size_t kn = (size_t)(t + 1) * BK;
    const bool more = (t < 63);

#pragma unroll
    for (int p = 0; p < 4; ++p) {
      // ---- ds_read this phase's A fragments (validated buffer) ----
#pragma unroll
      for (int j = 0; j < 2; ++j)
        af[j] = *(const i32x4*)&Ab[(wm + (p * 2 + j) * 16 + l16) * BK + pos];

      // ---- p0: prefetch next tile's B frags (global->reg) + stage next A --
      if (more && p == 0) {
#pragma unroll
        for (int ni = 0; ni < 4; ++ni)
          bfn[ni] = *(const i32x4*)(bgf[ni] + kn);
        gl2lds16(ag0 + kn, An + lA0);
        gl2lds16(ag1 + kn, An + lA1);
      }
      __builtin_amdgcn_s_barrier();
      __builtin_amdgcn_s_setprio(1);
#pragma unroll
      for (int j = 0; j < 2; ++j)
#pragma unroll
        for (int ni = 0; ni < 4; ++ni)
          acc[p * 2 + j][ni] = __builtin_amdgcn_mfma_i32_16x16x64_i8(
              af[j], bf[ni], acc[p * 2 + j][ni], 0, 0, 0);
      __builtin_amdgcn_s_setprio(0);
      if (p < 3) __builtin_amdgcn_s_barrier();
    }
    __syncthreads();  // drains vmcnt(0): next A tile + bfn resident
    if (more) {
#pragma unroll
      for (int ni = 0; ni < 4; ++ni) bf[ni] = bfn[ni];
    }
  }

  // ---- epilogue ----
  const float alpha = alpha_p[0];
#pragma unroll
  for (int mi = 0; mi < 8; ++mi) {
#pragma unroll
    for (int r2 = 0; r2 < 4; ++r2) {
      const int m = bm + wm + mi * 16 + quad * 4 + r2;
      const float s = (alpha * gamma[m]) / 127.0f;
#pragma unroll
      for (int ni = 0; ni < 4; ++ni) {
        const int n = bn + wn + ni * 16 + l16;
        out[(size_t)m * ND + n] = (float)acc[mi][ni][r2] * s;
      }
    }
  }
}

// --------------------------------------------------------------------------

extern "C" void kernel_launch(void* const* d_in, const int* in_sizes, int n_in,
                              void* d_out, int out_size, void* d_ws, size_t ws_size,
                              hipStream_t stream) {
  const float* x = (const float*)d_in[0];
  const float* w = (const float*)d_in[1];
  const float* nw = (const float*)d_in[2];
  float* out = (float*)d_out;

  char* ws = (char*)d_ws;
  signed char* xq = (signed char*)ws;
  signed char* wq = (signed char*)(ws + ((size_t)1 << 24));
  float* gamma = (float*)(ws + ((size_t)2 << 24));
  float* part = (float*)(ws + ((size_t)2 << 24) + 16384);
  float* alpha = (float*)(ws + ((size_t)2 << 24) + 32768);

  k_alpha_part<<<4096, 256, 0, stream>>>(w, part);
  k_quant_all<<<4096 + WBLK, 256, 0, stream>>>(w, x, nw, part, wq, xq, gamma, alpha);
  k_gemm<<<dim3(256), dim3(512), 0, stream>>>(xq, wq, gamma, alpha, out);
}

// Round 7
// 231.691 us; speedup vs baseline: 1.1332x; 1.1332x over previous
//
#include <hip/hip_runtime.h>
#include <cstdint>
#include <cstddef>

// FusedBitLinear: RMSNorm -> ternary W quant (absmean) -> int8 activation quant
// -> int GEMM (MFMA i8) -> rescale by alpha*gamma[m]/127.
//
// M=4096 tokens, K=4096, N=4096. fp32 in/out.
//
// ws layout:
//   [0, 16M)            xq   int8 [4096][4096]
//   [16M, 32M)          wq   int8 [4096][4096]
//   [32M, +16KB)        gamma float[4096]
//   [+16KB, +32KB)      alpha partials float[4096]
//   [+32KB, +4B)        alpha float[1]

#define KD 4096
#define MD 4096
#define ND 4096

#define WBLK 512

typedef int i32x4 __attribute__((ext_vector_type(4)));

// async global->LDS, 16B per lane; lds dst is wave-uniform base (+lane*16)
__device__ __forceinline__ void gl2lds16(const signed char* g, signed char* l) {
  __builtin_amdgcn_global_load_lds(
      (const __attribute__((address_space(1))) void*)g,
      (__attribute__((address_space(3))) void*)l, 16, 0, 0);
}

__device__ __forceinline__ float wave_sum(float v) {
#pragma unroll
  for (int off = 32; off; off >>= 1) v += __shfl_down(v, off, 64);
  return v;
}
__device__ __forceinline__ float wave_max(float v) {
#pragma unroll
  for (int off = 32; off; off >>= 1) v = fmaxf(v, __shfl_down(v, off, 64));
  return v;
}

// ---------------- pass 1: per-row |W| partial sums (UNCHANGED) ------------

__global__ __launch_bounds__(256) void k_alpha_part(const float* __restrict__ w,
                                                    float* __restrict__ part) {
  __shared__ float red[4];
  const int tid = threadIdx.x;
  const float4* w4 = (const float4*)(w + (size_t)blockIdx.x * 4096);
  float s = 0.f;
#pragma unroll
  for (int i = 0; i < 4; ++i) {
    float4 v = w4[i * 256 + tid];
    s += fabsf(v.x) + fabsf(v.y) + fabsf(v.z) + fabsf(v.w);
  }
  s = wave_sum(s);
  if ((tid & 63) == 0) red[tid >> 6] = s;
  __syncthreads();
  if (tid == 0) part[blockIdx.x] = (red[0] + red[1]) + (red[2] + red[3]);
}

// ---------------- pass 2: fused quantization (UNCHANGED) ------------------

__device__ __forceinline__ uint32_t qw4(float4 v, float alpha) {
  int q0 = (int)fminf(fmaxf(rintf(v.x / alpha), -1.f), 1.f);
  int q1 = (int)fminf(fmaxf(rintf(v.y / alpha), -1.f), 1.f);
  int q2 = (int)fminf(fmaxf(rintf(v.z / alpha), -1.f), 1.f);
  int q3 = (int)fminf(fmaxf(rintf(v.w / alpha), -1.f), 1.f);
  return (uint32_t)(q0 & 255) | ((uint32_t)(q1 & 255) << 8) |
         ((uint32_t)(q2 & 255) << 16) | ((uint32_t)(q3 & 255) << 24);
}

__global__ __launch_bounds__(256) void k_quant_all(const float* __restrict__ w,
                                                   const float* __restrict__ x,
                                                   const float* __restrict__ nw,
                                                   const float* __restrict__ part,
                                                   signed char* __restrict__ wq,
                                                   signed char* __restrict__ xq,
                                                   float* __restrict__ gamma,
                                                   float* __restrict__ alpha_out) {
  const int tid = threadIdx.x;
  const int bid = blockIdx.x;
  __shared__ float red[4];
  __shared__ float red2[4];

  if (bid < 4096) {
    const int row = bid;
    const float4* x4 = (const float4*)(x + (size_t)row * 4096);
    const float4* n4 = (const float4*)nw;
    float4 xv[4], nv[4];
#pragma unroll
    for (int i = 0; i < 4; ++i) {
      xv[i] = x4[i * 256 + tid];
      nv[i] = n4[i * 256 + tid];
    }
    float ss = 0.f, mx = 0.f;
#pragma unroll
    for (int i = 0; i < 4; ++i) {
      ss += xv[i].x * xv[i].x + xv[i].y * xv[i].y + xv[i].z * xv[i].z +
            xv[i].w * xv[i].w;
      mx = fmaxf(mx,
                 fmaxf(fmaxf(fabsf(xv[i].x * nv[i].x), fabsf(xv[i].y * nv[i].y)),
                       fmaxf(fabsf(xv[i].z * nv[i].z), fabsf(xv[i].w * nv[i].w))));
    }
    ss = wave_sum(ss);
    mx = wave_max(mx);
    if ((tid & 63) == 0) {
      red[tid >> 6] = ss;
      red2[tid >> 6] = mx;
    }
    __syncthreads();
    const float tot = (red[0] + red[1]) + (red[2] + red[3]);
    const float rms = sqrtf(tot * (1.0f / 4096.0f) + 1e-6f);
    const float mxr = fmaxf(fmaxf(red2[0], red2[1]), fmaxf(red2[2], red2[3]));
    const float g = fmaxf(mxr / rms, 1e-10f);
    if (tid == 0) gamma[row] = g;
    const float inv = 127.0f / (rms * g);

    uint32_t* xqi = (uint32_t*)(xq + (size_t)row * 4096);
#pragma unroll
    for (int i = 0; i < 4; ++i) {
      const int f = i * 256 + tid;
      int q0 = (int)fminf(fmaxf(rintf(xv[i].x * nv[i].x * inv), -128.f), 127.f);
      int q1 = (int)fminf(fmaxf(rintf(xv[i].y * nv[i].y * inv), -128.f), 127.f);
      int q2 = (int)fminf(fmaxf(rintf(xv[i].z * nv[i].z * inv), -128.f), 127.f);
      int q3 = (int)fminf(fmaxf(rintf(xv[i].w * nv[i].w * inv), -128.f), 127.f);
      xqi[f] = (uint32_t)(q0 & 255) | ((uint32_t)(q1 & 255) << 8) |
               ((uint32_t)(q2 & 255) << 16) | ((uint32_t)(q3 & 255) << 24);
    }
  } else {
    const int wb = bid - 4096;
    float s = 0.f;
#pragma unroll
    for (int i = 0; i < 16; ++i) s += part[i * 256 + tid];
    s = wave_sum(s);
    if ((tid & 63) == 0) red[tid >> 6] = s;
    __syncthreads();
    const float alpha =
        fmaxf(((red[0] + red[1]) + (red[2] + red[3])) * (1.0f / 16777216.0f),
              1e-10f);
    if (wb == 0 && tid == 0) alpha_out[0] = alpha;

    const float4* w4 = (const float4*)w;
    uint32_t* wqi = (uint32_t*)wq;
#pragma unroll 1
    for (int k = 0; k < 32; k += 4) {
      const int f0 = (wb * 32 + k) * 256 + tid;
      float4 v0 = w4[f0];
      float4 v1 = w4[f0 + 256];
      float4 v2 = w4[f0 + 512];
      float4 v3 = w4[f0 + 768];
      wqi[f0] = qw4(v0, alpha);
      wqi[f0 + 256] = qw4(v1, alpha);
      wqi[f0 + 512] = qw4(v2, alpha);
      wqi[f0 + 768] = qw4(v3, alpha);
    }
  }
}

// ------------- int8 GEMM: y[m,n] = (xq . wq^T) * alpha*gamma[m]/127 -------
// 256x256 tile, BK=64, 8 waves (2M x 4N), per-wave 128x64 = 8x4 frags of
// 16x16 via mfma_i32_16x16x64_i8. Structure = r3 (best measured, 77.7 us)
// EXCEPT the sync depth.
//
// ROUND-7 CHANGE: COUNTED VMCNT + 3-BUFFER, 2-TILE-AHEAD PREFETCH (T4).
// Diagnosis: every prior round (r0/r3/r4/r5/r6) drains vmcnt to ZERO once
// per tile — the exact "8-phase with drain-0 ≈ 1-phase ≈ 36%" plateau the
// bf16 ladder measured (m218 V1). MfmaUtil pinned at 32-35% in all five
// variants confirms it. The proven fix (m218 V0, +38%@4k/+73%@8k) is loads
// IN FLIGHT ACROSS the barrier:
//   - 3 LDS buffers (3 x 32 KB = 96 KB static).
//   - During tile t: stage tile t+2 (A at p0, B at p1; 4 gl2lds/wave).
//   - End of tile t: per-wave s_waitcnt vmcnt(4) + raw s_barrier. The 4
//     loads needed (t+1's) were issued a full tile (~2900 cyc) ago ->
//     wait is ~free; t+2's 4 loads REMAIN IN FLIGHT across the barrier.
//     vmcnt(0) only at t=62 (nothing newer in flight). Never in steady state.
// Safety: per-wave vmcnt(4)+all-wave barrier => all t+1 loads landed before
// any wave reads them. Buffer (t+2)%3's last reads (tile t-1) are consumed
// into registers (lgkm-waited by their MFMAs) before the end-of-(t-1)
// barrier, before stage(t+2) issues.
//
// Kept from r3/r5: per-phase 2-barrier cadence, setprio around MFMA, A+B in
// LDS, verified swizzle (0 conflicts), rect XCD remap (FETCH 73.8->49.2 MB).
// Swizzle: LDS chunk p of row R holds src chunk p ^ ((R>>1)&3); staging lane
// l -> row +(l>>2), pos (l&3), src (l&3)^((l>>3)&3); read pos =
// quad ^ ((l16>>1)&3). A/B frag byte j: k = quad*16+j, m/n = lane&15.
// C/D: col = lane&15, row = quad*4 + reg (verified r0).

#define BM 256
#define BN 256
#define BK 64

__global__ __launch_bounds__(512, 2) void k_gemm(const signed char* __restrict__ xq,
                                                 const signed char* __restrict__ wq,
                                                 const float* __restrict__ gamma,
                                                 const float* __restrict__ alpha_p,
                                                 float* __restrict__ out) {
  __shared__ __align__(16) signed char As_[3 * 32768];  // 96 KB, 3 buffers
  const int tid = threadIdx.x;
  const int lane = tid & 63;
  const int wave = tid >> 6;         // 0..7
  const int wm = (wave >> 2) * 128;  // 0 or 128
  const int wn = (wave & 3) * 64;    // 0..192
  const int quad = lane >> 4;
  const int l16 = lane & 15;

  // XCD-aware bijective remap: XCD x gets a 4(bm) x 8(bn) rectangle.
  const int x = blockIdx.x & 7;
  const int r = blockIdx.x >> 3;  // 0..31
  const int bm = ((x & 3) * 4 + (r >> 3)) * BM;
  const int bn = ((x >> 2) * 8 + (r & 7)) * BN;

  // staging: wave w, line j (j=0,1) covers rows [(j*8+w)*16, +16).
  const int lr = lane >> 2;
  const int sc = (lane & 3) ^ ((lane >> 3) & 3);
  const int rb0 = wave * 16;
  const int rb1 = (8 + wave) * 16;
  const signed char* ag0 = xq + (size_t)(bm + rb0 + lr) * KD + sc * 16;
  const signed char* ag1 = xq + (size_t)(bm + rb1 + lr) * KD + sc * 16;
  const signed char* bg0 = wq + (size_t)(bn + rb0 + lr) * KD + sc * 16;
  const signed char* bg1 = wq + (size_t)(bn + rb1 + lr) * KD + sc * 16;
  const int lA0 = rb0 * BK;
  const int lA1 = rb1 * BK;

  const int pos = (quad ^ ((l16 >> 1) & 3)) * 16;

  i32x4 acc[8][4];
#pragma unroll
  for (int i = 0; i < 8; ++i)
#pragma unroll
    for (int j = 0; j < 4; ++j) acc[i][j] = (i32x4){0, 0, 0, 0};

  // ---- prologue: stage tile 0 -> buf0, tile 1 -> buf1; counted wait ----
  gl2lds16(ag0, As_ + lA0);
  gl2lds16(ag1, As_ + lA1);
  gl2lds16(bg0, As_ + 16384 + lA0);
  gl2lds16(bg1, As_ + 16384 + lA1);
  gl2lds16(ag0 + BK, As_ + 32768 + lA0);
  gl2lds16(ag1 + BK, As_ + 32768 + lA1);
  gl2lds16(bg0 + BK, As_ + 32768 + 16384 + lA0);
  gl2lds16(bg1 + BK, As_ + 32768 + 16384 + lA1);
  asm volatile("s_waitcnt vmcnt(4)" ::: "memory");  // tile 0 landed; tile 1 in flight
  __builtin_amdgcn_s_barrier();

  int cb = 0;  // buffer holding tile t
  for (int t = 0; t < 64; ++t) {
    const signed char* Ab = As_ + cb * 32768;
    const signed char* Bb = Ab + 16384;
    const int sb = (cb == 0) ? 2 : cb - 1;  // (t+2)%3
    signed char* An = As_ + sb * 32768;
    signed char* Bn = An + 16384;
    const size_t kn = (size_t)(t + 2) * BK;
    const bool st = (t < 62);  // stage tile t+2?

    i32x4 bf[4], af[2];

#pragma unroll
    for (int p = 0; p < 4; ++p) {
      // ---- ds_read this phase's fragments (validated buffer) ----
      if (p == 0) {
#pragma unroll
        for (int ni = 0; ni < 4; ++ni)
          bf[ni] = *(const i32x4*)&Bb[(wn + ni * 16 + l16) * BK + pos];
      }
#pragma unroll
      for (int j = 0; j < 2; ++j)
        af[j] = *(const i32x4*)&Ab[(wm + (p * 2 + j) * 16 + l16) * BK + pos];

      // ---- stage tile t+2 into buffer (t+2)%3 (A at p0, B at p1) ----
      if (st) {
        if (p == 0) {
          gl2lds16(ag0 + kn, An + lA0);
          gl2lds16(ag1 + kn, An + lA1);
        } else if (p == 1) {
          gl2lds16(bg0 + kn, Bn + lA0);
          gl2lds16(bg1 + kn, Bn + lA1);
        }
      }
      __builtin_amdgcn_s_barrier();
      __builtin_amdgcn_s_setprio(1);
#pragma unroll
      for (int j = 0; j < 2; ++j)
#pragma unroll
        for (int ni = 0; ni < 4; ++ni)
          acc[p * 2 + j][ni] = __builtin_amdgcn_mfma_i32_16x16x64_i8(
              af[j], bf[ni], acc[p * 2 + j][ni], 0, 0, 0);
      __builtin_amdgcn_s_setprio(0);
      if (p < 3) __builtin_amdgcn_s_barrier();
    }

    // ---- end of tile: COUNTED wait — t+1's loads landed, t+2's stay in
    //      flight across the barrier (the T4 mechanism; never vmcnt(0) in
    //      steady state) ----
    if (t < 62) {
      asm volatile("s_waitcnt vmcnt(4)" ::: "memory");
      __builtin_amdgcn_s_barrier();
    } else if (t == 62) {
      asm volatile("s_waitcnt vmcnt(0)" ::: "memory");
      __builtin_amdgcn_s_barrier();
    }
    cb = (cb == 2) ? 0 : cb + 1;
  }

  // ---- epilogue ----
  const float alpha = alpha_p[0];
#pragma unroll
  for (int mi = 0; mi < 8; ++mi) {
#pragma unroll
    for (int r2 = 0; r2 < 4; ++r2) {
      const int m = bm + wm + mi * 16 + quad * 4 + r2;
      const float s = (alpha * gamma[m]) / 127.0f;
#pragma unroll
      for (int ni = 0; ni < 4; ++ni) {
        const int n = bn + wn + ni * 16 + l16;
        out[(size_t)m * ND + n] = (float)acc[mi][ni][r2] * s;
      }
    }
  }
}

// --------------------------------------------------------------------------

extern "C" void kernel_launch(void* const* d_in, const int* in_sizes, int n_in,
                              void* d_out, int out_size, void* d_ws, size_t ws_size,
                              hipStream_t stream) {
  const float* x = (const float*)d_in[0];
  const float* w = (const float*)d_in[1];
  const float* nw = (const float*)d_in[2];
  float* out = (float*)d_out;

  char* ws = (char*)d_ws;
  signed char* xq = (signed char*)ws;
  signed char* wq = (signed char*)(ws + ((size_t)1 << 24));
  float* gamma = (float*)(ws + ((size_t)2 << 24));
  float* part = (float*)(ws + ((size_t)2 << 24) + 16384);
  float* alpha = (float*)(ws + ((size_t)2 << 24) + 32768);

  k_alpha_part<<<4096, 256, 0, stream>>>(w, part);
  k_quant_all<<<4096 + WBLK, 256, 0, stream>>>(w, x, nw, part, wq, xq, gamma, alpha);
  k_gemm<<<dim3(256), dim3(512), 0, stream>>>(xq, wq, gamma, alpha, out);
}